// Round 1
// baseline (322.913 us; speedup 1.0000x reference)
//
#include <hip/hip_runtime.h>
#include <stdint.h>

typedef _Float16 f16;
typedef _Float16 f16x4 __attribute__((ext_vector_type(4)));
typedef _Float16 f16x8 __attribute__((ext_vector_type(8)));
typedef float f32x4 __attribute__((ext_vector_type(4)));

#define D_MODEL 1024
#define N_HEAD 16
#define BATCH 2
#define SEQ 2048
#define MTOT (BATCH * SEQ)  // 4096

// async global->LDS, 16B per lane; LDS dest = wave-uniform base + lane*16
__device__ __forceinline__ void llds16(const void* g, void* l) {
  __builtin_amdgcn_global_load_lds(
      (const __attribute__((address_space(1))) unsigned int*)g,
      (__attribute__((address_space(3))) unsigned int*)l, 16, 0, 0);
}

// ---- fp32 -> fp16 convert, 4 elems/thread ----
__global__ void k_cvt(const float* __restrict__ src, f16* __restrict__ dst, int n) {
  int i = (blockIdx.x * blockDim.x + threadIdx.x) * 4;
  if (i < n) {
    const float4 v = *(const float4*)(src + i);
    f16x4 o;
    o.x = (f16)v.x; o.y = (f16)v.y; o.z = (f16)v.z; o.w = (f16)v.w;
    *(f16x4*)(dst + i) = o;
  }
}

// ---- W [K][N] fp32 -> WT [N][K] fp16 (tiled transpose) ----
__global__ void k_tw(const float* __restrict__ W, f16* __restrict__ WT) {
  __shared__ float t[32][33];
  const int bx = blockIdx.x * 32;  // n tile
  const int by = blockIdx.y * 32;  // k tile
  const int tx = threadIdx.x, ty = threadIdx.y;
#pragma unroll
  for (int i = 0; i < 32; i += 8)
    t[ty + i][tx] = W[(size_t)(by + ty + i) * D_MODEL + bx + tx];
  __syncthreads();
#pragma unroll
  for (int i = 0; i < 32; i += 8)
    WT[(size_t)(bx + ty + i) * D_MODEL + by + tx] = (f16)t[tx][ty + i];
}

// ---- GEMM: C[M,1024] = A[M,1024](f16) @ B (given as BT[1024,1024] f16) + bias ----
// 128x128 tile, BK=64, 4 waves (2x2), swizzled global_load_lds staging.
template <bool OUTF32>
__global__ __launch_bounds__(256) void k_gemm(const f16* __restrict__ A,
                                              const f16* __restrict__ BT,
                                              const float* __restrict__ bias,
                                              void* __restrict__ Cout) {
  constexpr int Kd = 1024, Nd = 1024;
  __shared__ __align__(16) f16 As[128 * 64];
  __shared__ __align__(16) f16 Bs[128 * 64];
  const int m0 = blockIdx.y * 128, n0 = blockIdx.x * 128;
  const int tid = threadIdx.x, w = tid >> 6, ln = tid & 63;
  const int wm = w >> 1, wn = w & 1;
  f32x4 acc[4][4] = {};
  for (int kt = 0; kt < Kd / 64; ++kt) {
    const int k0 = kt * 64;
#pragma unroll
    for (int i = 0; i < 4; ++i) {
      const int c = w * 4 + i;            // chunk 0..15 (1KB each)
      const int r = c * 8 + (ln >> 3);    // row 0..127
      const int g = ln & 7;               // 16B granule within 128B row
      const int koff = k0 + ((g ^ (r & 7)) * 8);  // pre-swizzled source
      llds16(A + (size_t)(m0 + r) * Kd + koff, As + c * 512);
      llds16(BT + (size_t)(n0 + r) * Kd + koff, Bs + c * 512);
    }
    __syncthreads();
#pragma unroll
    for (int kk = 0; kk < 2; ++kk) {
      f16x8 af[4], bf[4];
#pragma unroll
      for (int mi = 0; mi < 4; ++mi) {
        const int r = wm * 64 + mi * 16 + (ln & 15);
        const int g = kk * 4 + (ln >> 4);
        af[mi] = *(const f16x8*)(As + r * 64 + ((g ^ (r & 7)) * 8));
      }
#pragma unroll
      for (int ni = 0; ni < 4; ++ni) {
        const int r = wn * 64 + ni * 16 + (ln & 15);
        const int g = kk * 4 + (ln >> 4);
        bf[ni] = *(const f16x8*)(Bs + r * 64 + ((g ^ (r & 7)) * 8));
      }
#pragma unroll
      for (int mi = 0; mi < 4; ++mi)
#pragma unroll
        for (int ni = 0; ni < 4; ++ni)
          acc[mi][ni] = __builtin_amdgcn_mfma_f32_16x16x32_f16(af[mi], bf[ni], acc[mi][ni], 0, 0, 0);
    }
    __syncthreads();
  }
#pragma unroll
  for (int mi = 0; mi < 4; ++mi)
#pragma unroll
    for (int ni = 0; ni < 4; ++ni)
#pragma unroll
      for (int r = 0; r < 4; ++r) {
        const int row = m0 + wm * 64 + mi * 16 + (ln >> 4) * 4 + r;
        const int col = n0 + wn * 64 + ni * 16 + (ln & 15);
        const float val = acc[mi][ni][r] + bias[col];
        if (OUTF32)
          ((float*)Cout)[(size_t)row * Nd + col] = val;
        else
          ((f16*)Cout)[(size_t)row * Nd + col] = (f16)val;
      }
}

// ---- fused sigmoid attention: per (q-tile 64, head, batch) block ----
// O[q][d] = sum_kv sigmoid(Q.K/8)[q][kv] * V[kv][d], streamed over kv tiles of 64.
__global__ __launch_bounds__(256) void k_attn(const f16* __restrict__ Qp,
                                              const f16* __restrict__ Kp,
                                              const f16* __restrict__ Vp,
                                              f16* __restrict__ ctx) {
  __shared__ __align__(16) f16 Ks[64 * 64];       // [kv][d] swizzled
  __shared__ __align__(16) f16 Vt[64 * 64];       // [d][kv] swizzled
  __shared__ __align__(16) f16 Pl[4][16 * 64];    // per-wave [q][kv] swizzled
  const int qt = blockIdx.x, h = blockIdx.y, b = blockIdx.z;
  const int tid = threadIdx.x, w = tid >> 6, ln = tid & 63;
  const int s0 = qt * 64;
  const f16* Qb = Qp + ((size_t)b * SEQ) * D_MODEL + h * 64;
  const f16* Kb = Kp + ((size_t)b * SEQ) * D_MODEL + h * 64;
  const f16* Vb = Vp + ((size_t)b * SEQ) * D_MODEL + h * 64;
  // Q fragments held in registers for the whole kernel (wave owns 16 q rows)
  f16x8 aq[2];
  {
    const int qrow = s0 + w * 16 + (ln & 15);
#pragma unroll
    for (int kk = 0; kk < 2; ++kk)
      aq[kk] = *(const f16x8*)(Qb + (size_t)qrow * D_MODEL + kk * 32 + (ln >> 4) * 8);
  }
  f32x4 oacc[4] = {};
  for (int kt = 0; kt < SEQ / 64; ++kt) {
    const int kv0 = kt * 64;
    // stage K tile [64][64] via swizzled global_load_lds (8 chunks, 2/wave)
#pragma unroll
    for (int i = 0; i < 2; ++i) {
      const int c = w * 2 + i;
      const int r = c * 8 + (ln >> 3);
      const int g = ln & 7;
      llds16(Kb + (size_t)(kv0 + r) * D_MODEL + ((g ^ (r & 7)) * 8), Ks + c * 512);
    }
    // stage V transposed [d][kv] (scalar writes; upgrade target: ds_read_b64_tr_b16)
    {
      const int kv = tid >> 2;
      const int d0 = (tid & 3) * 16;
      const f16* vsrc = Vb + (size_t)(kv0 + kv) * D_MODEL + d0;
      f16x8 v0 = *(const f16x8*)(vsrc);
      f16x8 v1 = *(const f16x8*)(vsrc + 8);
      const int gv = kv >> 3, e = kv & 7;
#pragma unroll
      for (int j = 0; j < 8; ++j) {
        const int d = d0 + j;
        Vt[d * 64 + ((gv ^ (d & 7)) * 8) + e] = v0[j];
      }
#pragma unroll
      for (int j = 0; j < 8; ++j) {
        const int d = d0 + 8 + j;
        Vt[d * 64 + ((gv ^ (d & 7)) * 8) + e] = v1[j];
      }
    }
    __syncthreads();
    // S = Q @ K^T  (wave: 16 q rows x 64 kv cols)
    f32x4 sacc[4] = {};
#pragma unroll
    for (int kk = 0; kk < 2; ++kk) {
      f16x8 bk[4];
#pragma unroll
      for (int nt = 0; nt < 4; ++nt) {
        const int kv = nt * 16 + (ln & 15);
        const int g = kk * 4 + (ln >> 4);
        bk[nt] = *(const f16x8*)(Ks + kv * 64 + ((g ^ (kv & 7)) * 8));
      }
#pragma unroll
      for (int nt = 0; nt < 4; ++nt)
        sacc[nt] = __builtin_amdgcn_mfma_f32_16x16x32_f16(aq[kk], bk[nt], sacc[nt], 0, 0, 0);
    }
    // P = sigmoid(S/8) -> per-wave LDS (swizzled) as fp16
#pragma unroll
    for (int nt = 0; nt < 4; ++nt)
#pragma unroll
      for (int r = 0; r < 4; ++r) {
        const float x = sacc[nt][r] * 0.125f;
        const float pv = 1.0f / (1.0f + __expf(-x));
        const int pr = (ln >> 4) * 4 + r;
        const int pc = nt * 16 + (ln & 15);
        Pl[w][pr * 64 + (((pc >> 3) ^ (pr & 7)) * 8) + (pc & 7)] = (f16)pv;
      }
    // O += P @ V
#pragma unroll
    for (int kk = 0; kk < 2; ++kk) {
      const int prr = ln & 15;
      const int ga = kk * 4 + (ln >> 4);
      const f16x8 ap = *(const f16x8*)(Pl[w] + prr * 64 + ((ga ^ (prr & 7)) * 8));
      f16x8 bv[4];
#pragma unroll
      for (int nt = 0; nt < 4; ++nt) {
        const int d = nt * 16 + (ln & 15);
        const int g = kk * 4 + (ln >> 4);
        bv[nt] = *(const f16x8*)(Vt + d * 64 + ((g ^ (d & 7)) * 8));
      }
#pragma unroll
      for (int nt = 0; nt < 4; ++nt)
        oacc[nt] = __builtin_amdgcn_mfma_f32_16x16x32_f16(ap, bv[nt], oacc[nt], 0, 0, 0);
    }
    __syncthreads();
  }
  // write ctx tile (bf16 layout [B,S,D], head h occupies cols h*64..h*64+63)
  f16* cb = ctx + ((size_t)b * SEQ + s0 + w * 16) * D_MODEL + h * 64;
#pragma unroll
  for (int nt = 0; nt < 4; ++nt)
#pragma unroll
    for (int r = 0; r < 4; ++r)
      cb[((ln >> 4) * 4 + r) * D_MODEL + nt * 16 + (ln & 15)] = (f16)oacc[nt][r];
}

extern "C" void kernel_launch(void* const* d_in, const int* in_sizes, int n_in,
                              void* d_out, int out_size, void* d_ws, size_t ws_size,
                              hipStream_t stream) {
  (void)in_sizes; (void)n_in; (void)out_size; (void)ws_size;
  const float* q  = (const float*)d_in[0];
  const float* k  = (const float*)d_in[1];
  const float* v  = (const float*)d_in[2];
  const float* Wq = (const float*)d_in[3];
  const float* bq = (const float*)d_in[4];
  const float* Wk = (const float*)d_in[5];
  const float* bk = (const float*)d_in[6];
  const float* Wv = (const float*)d_in[7];
  const float* bv = (const float*)d_in[8];
  const float* Wo = (const float*)d_in[9];
  const float* bo = (const float*)d_in[10];
  float* out = (float*)d_out;

  char* p = (char*)d_ws;
  const size_t SZ_X = (size_t)MTOT * D_MODEL * sizeof(f16);     // 8 MB
  const size_t SZ_W = (size_t)D_MODEL * D_MODEL * sizeof(f16);  // 2 MB
  f16* qb  = (f16*)p; p += SZ_X;
  f16* kb  = (f16*)p; p += SZ_X;
  f16* vb  = (f16*)p; p += SZ_X;
  f16* WqT = (f16*)p; p += SZ_W;
  f16* WkT = (f16*)p; p += SZ_W;
  f16* WvT = (f16*)p; p += SZ_W;
  f16* WoT = (f16*)p; p += SZ_W;
  f16* Qp  = (f16*)p; p += SZ_X;
  f16* Kp  = (f16*)p; p += SZ_X;
  f16* Vp  = (f16*)p; p += SZ_X;
  f16* ctx = (f16*)p; p += SZ_X;

  const int n = MTOT * D_MODEL;  // 4194304
  k_cvt<<<n / 4 / 256, 256, 0, stream>>>(q, qb, n);
  k_cvt<<<n / 4 / 256, 256, 0, stream>>>(k, kb, n);
  k_cvt<<<n / 4 / 256, 256, 0, stream>>>(v, vb, n);
  dim3 tb(32, 8);
  k_tw<<<dim3(32, 32), tb, 0, stream>>>(Wq, WqT);
  k_tw<<<dim3(32, 32), tb, 0, stream>>>(Wk, WkT);
  k_tw<<<dim3(32, 32), tb, 0, stream>>>(Wv, WvT);
  k_tw<<<dim3(32, 32), tb, 0, stream>>>(Wo, WoT);
  k_gemm<false><<<dim3(8, 32), 256, 0, stream>>>(qb, WqT, bq, Qp);
  k_gemm<false><<<dim3(8, 32), 256, 0, stream>>>(kb, WkT, bk, Kp);
  k_gemm<false><<<dim3(8, 32), 256, 0, stream>>>(vb, WvT, bv, Vp);
  k_attn<<<dim3(SEQ / 64, N_HEAD, BATCH), 256, 0, stream>>>(Qp, Kp, Vp, ctx);
  k_gemm<true><<<dim3(8, 32), 256, 0, stream>>>(ctx, WoT, bo, out);
}

// Round 2
// 245.480 us; speedup vs baseline: 1.3154x; 1.3154x over previous
//
#include <hip/hip_runtime.h>
#include <stdint.h>

typedef _Float16 f16;
typedef _Float16 f16x4 __attribute__((ext_vector_type(4)));
typedef _Float16 f16x8 __attribute__((ext_vector_type(8)));
typedef float f32x4 __attribute__((ext_vector_type(4)));

#define D_MODEL 1024
#define N_HEAD 16
#define BATCH 2
#define SEQ 2048
#define MTOT 4096
#define NQKV 3072

__device__ __forceinline__ void llds16(const void* g, void* l) {
  __builtin_amdgcn_global_load_lds(
      (const __attribute__((address_space(1))) unsigned int*)g,
      (__attribute__((address_space(3))) unsigned int*)l, 16, 0, 0);
}

__device__ __forceinline__ float fast_rcp(float x) {
#if __has_builtin(__builtin_amdgcn_rcpf)
  return __builtin_amdgcn_rcpf(x);
#else
  return 1.0f / x;
#endif
}

// ---- fp32 -> fp16 convert ----
__global__ void k_cvt(const float* __restrict__ src, f16* __restrict__ dst, int n) {
  int i = (blockIdx.x * blockDim.x + threadIdx.x) * 4;
  if (i < n) {
    const float4 v = *(const float4*)(src + i);
    f16x4 o;
    o.x = (f16)v.x; o.y = (f16)v.y; o.z = (f16)v.z; o.w = (f16)v.w;
    *(f16x4*)(dst + i) = o;
  }
}

// ---- all 4 weights [K][N] fp32 -> [N][K] fp16 in one launch ----
__global__ void k_tw(const float* __restrict__ Wq, const float* __restrict__ Wk,
                     const float* __restrict__ Wv, const float* __restrict__ Wo,
                     f16* __restrict__ WqkvT, f16* __restrict__ WoT) {
  __shared__ float t[32][33];
  const int z = blockIdx.z;
  const float* W = (z == 0) ? Wq : (z == 1) ? Wk : (z == 2) ? Wv : Wo;
  f16* dst = (z < 3) ? (WqkvT + (size_t)z * 1024 * 1024) : WoT;
  const int bx = blockIdx.x * 32, by = blockIdx.y * 32;
  const int tx = threadIdx.x, ty = threadIdx.y;
#pragma unroll
  for (int i = 0; i < 32; i += 8)
    t[ty + i][tx] = W[(size_t)(by + ty + i) * 1024 + bx + tx];
  __syncthreads();
#pragma unroll
  for (int i = 0; i < 32; i += 8)
    dst[(size_t)(bx + ty + i) * 1024 + by + tx] = (f16)t[tx][ty + i];
}

// ---- GEMM: C[4096, Nd] ; n-block selects (A, bias) for fused QKV ----
// 128x128 tile, BK=64, 8 waves (2Mx4N, per-wave 64x32), 2-phase dbuf staging.
template <int Nd, bool OUTF32>
__global__ __launch_bounds__(512, 4) void k_gemm(const f16* __restrict__ A0,
                                                 const f16* __restrict__ A1,
                                                 const f16* __restrict__ A2,
                                                 const f16* __restrict__ BT,
                                                 const float* __restrict__ b0,
                                                 const float* __restrict__ b1,
                                                 const float* __restrict__ b2,
                                                 void* __restrict__ Cout) {
  constexpr int Kd = 1024;
  constexpr int NBX = Nd / 128;
  constexpr int NWG = (MTOT / 128) * NBX;
  __shared__ __align__(16) f16 As[2][8192];
  __shared__ __align__(16) f16 Bs[2][8192];
  int id = blockIdx.x;
  id = (id & 7) * (NWG / 8) + (id >> 3);  // XCD-aware swizzle (NWG % 8 == 0)
  const int n0 = (id % NBX) * 128, m0 = (id / NBX) * 128;
  const f16* A = (Nd == 1024) ? A0 : (n0 < 1024 ? A0 : n0 < 2048 ? A1 : A2);
  const int tid = threadIdx.x, w = tid >> 6, ln = tid & 63;
  const int wm = w >> 2, wn = w & 3;
  f32x4 acc[4][2] = {};

  auto stage = [&](int buf, int kt) {
    const int k0 = kt * 64;
#pragma unroll
    for (int i = 0; i < 2; ++i) {
      const int c = w * 2 + i;          // 1KB chunks, 16 total
      const int r = c * 8 + (ln >> 3);  // row 0..127
      const int g = ln & 7;
      const int ko = k0 + ((g ^ (r & 7)) * 8);
      llds16(A + (size_t)(m0 + r) * Kd + ko, &As[buf][c * 512]);
      llds16(BT + (size_t)(n0 + r) * Kd + ko, &Bs[buf][c * 512]);
    }
  };
  stage(0, 0);
  __syncthreads();
  int cur = 0;
  for (int kt = 0; kt < Kd / 64; ++kt) {
    if (kt < Kd / 64 - 1) stage(cur ^ 1, kt + 1);
#pragma unroll
    for (int kk = 0; kk < 2; ++kk) {
      f16x8 af[4], bf[2];
#pragma unroll
      for (int mi = 0; mi < 4; ++mi) {
        const int r = wm * 64 + mi * 16 + (ln & 15);
        const int g = kk * 4 + (ln >> 4);
        af[mi] = *(const f16x8*)(&As[cur][r * 64 + ((g ^ (r & 7)) * 8)]);
      }
#pragma unroll
      for (int nf = 0; nf < 2; ++nf) {
        const int r = wn * 32 + nf * 16 + (ln & 15);
        const int g = kk * 4 + (ln >> 4);
        bf[nf] = *(const f16x8*)(&Bs[cur][r * 64 + ((g ^ (r & 7)) * 8)]);
      }
#pragma unroll
      for (int mi = 0; mi < 4; ++mi)
#pragma unroll
        for (int nf = 0; nf < 2; ++nf)
          acc[mi][nf] = __builtin_amdgcn_mfma_f32_16x16x32_f16(af[mi], bf[nf], acc[mi][nf], 0, 0, 0);
    }
    __syncthreads();
    cur ^= 1;
  }
  const float* bb = (Nd == 1024) ? b0 : (n0 < 1024 ? b0 : n0 < 2048 ? b1 : b2);
  const int nb = n0 & 1023;
#pragma unroll
  for (int mi = 0; mi < 4; ++mi)
#pragma unroll
    for (int nf = 0; nf < 2; ++nf)
#pragma unroll
      for (int r = 0; r < 4; ++r) {
        const int row = m0 + wm * 64 + mi * 16 + (ln >> 4) * 4 + r;
        const int cl = wn * 32 + nf * 16 + (ln & 15);
        const float val = acc[mi][nf][r] + bb[nb + cl];
        if (OUTF32)
          ((float*)Cout)[(size_t)row * Nd + n0 + cl] = val;
        else
          ((f16*)Cout)[(size_t)row * Nd + n0 + cl] = (f16)val;
      }
}

// ---- V pre-transpose: QKV[:, 2048+h*64+d] -> Vt[(b,h), d, s] ----
__global__ void k_tv(const f16* __restrict__ QKV, f16* __restrict__ Vt) {
  const int sb = blockIdx.x, h = blockIdx.y, b = blockIdx.z;
  const int t = threadIdx.x;
  const int d = t & 63, si = (t >> 6) * 16;
  const int s0 = sb * 64 + si;
  const f16* src = QKV + ((size_t)b * SEQ + s0) * NQKV + 2048 + h * 64 + d;
  f16x8 v0, v1;
#pragma unroll
  for (int j = 0; j < 8; ++j) v0[j] = src[(size_t)j * NQKV];
#pragma unroll
  for (int j = 0; j < 8; ++j) v1[j] = src[(size_t)(j + 8) * NQKV];
  f16* dst = Vt + ((size_t)(b * N_HEAD + h) * 64 + d) * SEQ + s0;
  *(f16x8*)dst = v0;
  *(f16x8*)(dst + 8) = v1;
}

// ---- fused sigmoid attention, swapped-QK^T, dbuf K/V staging ----
__global__ __launch_bounds__(256, 4) void k_attn(const f16* __restrict__ QKV,
                                                 const f16* __restrict__ Vt,
                                                 f16* __restrict__ ctx) {
  __shared__ __align__(16) f16 Ks[2][4096];  // [kv][d] swizzled
  __shared__ __align__(16) f16 Vs[2][4096];  // [d][kv] swizzled
  __shared__ __align__(16) f16 Pl[4][1024];  // per-wave [q=16][kv=64] swizzled
  int id = blockIdx.x;
  id = (id & 7) * 128 + (id >> 3);  // XCD swizzle: each XCD works 4 (b,h) groups
  const int qt = id & 31, h = (id >> 5) & 15, b = id >> 9;
  const int tid = threadIdx.x, w = tid >> 6, ln = tid & 63;
  const int s0 = qt * 64;
  const f16* Qb = QKV + ((size_t)b * SEQ) * NQKV + h * 64;
  const f16* Kb = QKV + ((size_t)b * SEQ) * NQKV + 1024 + h * 64;
  const f16* Vtb = Vt + (size_t)(b * N_HEAD + h) * 64 * SEQ;
  const int q = ln & 15;
  // Q B-fragments in registers for whole kernel (wave owns q rows s0+w*16..+15)
  f16x8 aq[2];
  {
    const int qrow = s0 + w * 16 + q;
#pragma unroll
    for (int kk = 0; kk < 2; ++kk)
      aq[kk] = *(const f16x8*)(Qb + (size_t)qrow * NQKV + kk * 32 + (ln >> 4) * 8);
  }
  f32x4 oacc[4] = {};
  auto stage = [&](int buf, int kt) {
    const int kv0 = kt * 64;
#pragma unroll
    for (int i = 0; i < 2; ++i) {
      const int c = w * 2 + i;
      const int r = c * 8 + (ln >> 3);
      const int g = ln & 7;
      llds16(Kb + (size_t)(kv0 + r) * NQKV + ((g ^ (r & 7)) * 8), &Ks[buf][c * 512]);
      llds16(Vtb + (size_t)r * SEQ + kv0 + ((g ^ (r & 7)) * 8), &Vs[buf][c * 512]);
    }
  };
  stage(0, 0);
  __syncthreads();
  int cur = 0;
  for (int kt = 0; kt < SEQ / 64; ++kt) {
    if (kt < SEQ / 64 - 1) stage(cur ^ 1, kt + 1);
    // S^T = K @ Q^T : lane holds S[q=ln&15][kv = nt*16 + (ln>>4)*4 + r]
    f32x4 sacc[4] = {};
#pragma unroll
    for (int kk = 0; kk < 2; ++kk) {
      f16x8 ak[4];
#pragma unroll
      for (int nt = 0; nt < 4; ++nt) {
        const int kv = nt * 16 + (ln & 15);
        const int g = kk * 4 + (ln >> 4);
        ak[nt] = *(const f16x8*)(&Ks[cur][kv * 64 + ((g ^ (kv & 7)) * 8)]);
      }
#pragma unroll
      for (int nt = 0; nt < 4; ++nt)
        sacc[nt] = __builtin_amdgcn_mfma_f32_16x16x32_f16(ak[nt], aq[kk], sacc[nt], 0, 0, 0);
    }
    // P = sigmoid(S/8): kv contiguous per lane -> packed b64 writes (swizzled)
#pragma unroll
    for (int nt = 0; nt < 4; ++nt) {
      f16x4 pk;
#pragma unroll
      for (int r = 0; r < 4; ++r) {
        const float e = __expf(sacc[nt][r] * -0.125f);
        pk[r] = (f16)fast_rcp(1.0f + e);
      }
      const int gw = nt * 4 + (ln >> 4);  // 8B granule index (16/row)
      *(f16x4*)(&Pl[w][q * 64 + ((gw ^ (2 * (q & 7))) * 4)]) = pk;
    }
    // O += P @ V
#pragma unroll
    for (int kk = 0; kk < 2; ++kk) {
      const int gr = kk * 8 + (ln >> 4) * 2;
      const f16x8 ap = *(const f16x8*)(&Pl[w][q * 64 + ((gr ^ (2 * (q & 7))) * 4)]);
      f16x8 bv[4];
#pragma unroll
      for (int nt = 0; nt < 4; ++nt) {
        const int d = nt * 16 + (ln & 15);
        const int g = kk * 4 + (ln >> 4);
        bv[nt] = *(const f16x8*)(&Vs[cur][d * 64 + ((g ^ (d & 7)) * 8)]);
      }
#pragma unroll
      for (int nt = 0; nt < 4; ++nt)
        oacc[nt] = __builtin_amdgcn_mfma_f32_16x16x32_f16(ap, bv[nt], oacc[nt], 0, 0, 0);
    }
    __syncthreads();
    cur ^= 1;
  }
  f16* cb = ctx + ((size_t)b * SEQ + s0 + w * 16) * D_MODEL + h * 64;
#pragma unroll
  for (int nt = 0; nt < 4; ++nt)
#pragma unroll
    for (int r = 0; r < 4; ++r)
      cb[((ln >> 4) * 4 + r) * D_MODEL + nt * 16 + (ln & 15)] = (f16)oacc[nt][r];
}

extern "C" void kernel_launch(void* const* d_in, const int* in_sizes, int n_in,
                              void* d_out, int out_size, void* d_ws, size_t ws_size,
                              hipStream_t stream) {
  (void)in_sizes; (void)n_in; (void)out_size; (void)ws_size;
  const float* q  = (const float*)d_in[0];
  const float* k  = (const float*)d_in[1];
  const float* v  = (const float*)d_in[2];
  const float* Wq = (const float*)d_in[3];
  const float* bq = (const float*)d_in[4];
  const float* Wk = (const float*)d_in[5];
  const float* bk = (const float*)d_in[6];
  const float* Wv = (const float*)d_in[7];
  const float* bv = (const float*)d_in[8];
  const float* Wo = (const float*)d_in[9];
  const float* bo = (const float*)d_in[10];
  float* out = (float*)d_out;

  char* p = (char*)d_ws;
  const size_t SZ_X = (size_t)MTOT * D_MODEL * sizeof(f16);  // 8 MB
  f16* qb    = (f16*)p; p += SZ_X;
  f16* kb    = (f16*)p; p += SZ_X;
  f16* vb    = (f16*)p; p += SZ_X;
  f16* WqkvT = (f16*)p; p += 3 * (size_t)1024 * 1024 * sizeof(f16);
  f16* WoT   = (f16*)p; p += (size_t)1024 * 1024 * sizeof(f16);
  f16* QKVb  = (f16*)p; p += (size_t)MTOT * NQKV * sizeof(f16);  // 24 MB
  f16* Vtb   = (f16*)p; p += SZ_X;
  f16* ctx   = (f16*)p; p += SZ_X;

  const int n = MTOT * D_MODEL;
  k_cvt<<<n / 4 / 256, 256, 0, stream>>>(q, qb, n);
  k_cvt<<<n / 4 / 256, 256, 0, stream>>>(k, kb, n);
  k_cvt<<<n / 4 / 256, 256, 0, stream>>>(v, vb, n);
  k_tw<<<dim3(32, 32, 4), dim3(32, 8), 0, stream>>>(Wq, Wk, Wv, Wo, WqkvT, WoT);
  k_gemm<NQKV, false><<<(MTOT / 128) * (NQKV / 128), 512, 0, stream>>>(
      qb, kb, vb, WqkvT, bq, bk, bv, QKVb);
  k_tv<<<dim3(SEQ / 64, N_HEAD, BATCH), 256, 0, stream>>>(QKVb, Vtb);
  k_attn<<<SEQ / 64 * N_HEAD * BATCH, 256, 0, stream>>>(QKVb, Vtb, ctx);
  k_gemm<1024, true><<<(MTOT / 128) * (1024 / 128), 512, 0, stream>>>(
      ctx, ctx, ctx, WoT, bo, bo, bo, out);
}

// Round 6
// 233.913 us; speedup vs baseline: 1.3805x; 1.0494x over previous
//
#include <hip/hip_runtime.h>
#include <stdint.h>

typedef _Float16 f16;
typedef _Float16 f16x4 __attribute__((ext_vector_type(4)));
typedef _Float16 f16x8 __attribute__((ext_vector_type(8)));
typedef float f32x4 __attribute__((ext_vector_type(4)));
typedef float f32x16 __attribute__((ext_vector_type(16)));
typedef unsigned int u32;

#define D_MODEL 1024
#define N_HEAD 16
#define BATCH 2
#define SEQ 2048
#define MTOT 4096
#define NQKV 3072

__device__ __forceinline__ void llds16(const void* g, void* l) {
  __builtin_amdgcn_global_load_lds(
      (const __attribute__((address_space(1))) unsigned int*)g,
      (__attribute__((address_space(3))) unsigned int*)l, 16, 0, 0);
}

__device__ __forceinline__ float fast_rcp(float x) {
#if __has_builtin(__builtin_amdgcn_rcpf)
  return __builtin_amdgcn_rcpf(x);
#else
  return 1.0f / x;
#endif
}

#define SIG(x) fast_rcp(1.0f + __expf((x) * -0.125f))

__device__ __forceinline__ u32 pk2(float a, float b) {
  auto h = __builtin_amdgcn_cvt_pkrtz(a, b);  // __fp16 ext_vector(2)
  return __builtin_bit_cast(u32, h);
}

// ---- fused fp32->fp16 convert of q,k,v (contiguous 12M-elem dest) ----
__global__ void k_cvt3(const float* __restrict__ q, const float* __restrict__ k,
                       const float* __restrict__ v, f16* __restrict__ dst) {
  const int idx = (blockIdx.x * 256 + threadIdx.x) * 8;
  const int seg = idx >> 22;
  const int off = idx & ((1 << 22) - 1);
  const float* s = (seg == 0) ? q : (seg == 1) ? k : v;
  const float4 a = *(const float4*)(s + off);
  const float4 b = *(const float4*)(s + off + 4);
  f16x8 o;
  o[0] = (f16)a.x; o[1] = (f16)a.y; o[2] = (f16)a.z; o[3] = (f16)a.w;
  o[4] = (f16)b.x; o[5] = (f16)b.y; o[6] = (f16)b.z; o[7] = (f16)b.w;
  *(f16x8*)(dst + idx) = o;
}

// ---- all 4 weights [K][N] fp32 -> [N][K] fp16 in one launch ----
__global__ void k_tw(const float* __restrict__ Wq, const float* __restrict__ Wk,
                     const float* __restrict__ Wv, const float* __restrict__ Wo,
                     f16* __restrict__ WqkvT, f16* __restrict__ WoT) {
  __shared__ float t[32][33];
  const int z = blockIdx.z;
  const float* W = (z == 0) ? Wq : (z == 1) ? Wk : (z == 2) ? Wv : Wo;
  f16* dst = (z < 3) ? (WqkvT + (size_t)z * 1024 * 1024) : WoT;
  const int bx = blockIdx.x * 32, by = blockIdx.y * 32;
  const int tx = threadIdx.x, ty = threadIdx.y;
#pragma unroll
  for (int i = 0; i < 32; i += 8)
    t[ty + i][tx] = W[(size_t)(by + ty + i) * 1024 + bx + tx];
  __syncthreads();
#pragma unroll
  for (int i = 0; i < 32; i += 8)
    dst[(size_t)(bx + ty + i) * 1024 + by + tx] = (f16)t[tx][ty + i];
}

// ---- GEMM: C[4096, Nd]. MODE 0: fused QKV, f16 out, V-third written transposed
//      to Vt[(b,h),d,s]. MODE 1: fp32 out (output projection). ----
template <int Nd, int MODE>
__global__ __launch_bounds__(512, 4) void k_gemm(const f16* __restrict__ A0,
                                                 const f16* __restrict__ A1,
                                                 const f16* __restrict__ A2,
                                                 const f16* __restrict__ BT,
                                                 const float* __restrict__ b0,
                                                 const float* __restrict__ b1,
                                                 const float* __restrict__ b2,
                                                 void* __restrict__ Cout,
                                                 f16* __restrict__ Vt) {
  constexpr int Kd = 1024;
  constexpr int NBX = Nd / 128;
  constexpr int NWG = (MTOT / 128) * NBX;
  __shared__ __align__(16) f16 As[2][8192];
  __shared__ __align__(16) f16 Bs[2][8192];
  int id = blockIdx.x;
  id = (id & 7) * (NWG / 8) + (id >> 3);
  const int n0 = (id % NBX) * 128, m0 = (id / NBX) * 128;
  const f16* A = (Nd == 1024) ? A0 : (n0 < 1024 ? A0 : n0 < 2048 ? A1 : A2);
  const int tid = threadIdx.x, w = tid >> 6, ln = tid & 63;
  const int wm = w >> 2, wn = w & 3;
  f32x4 acc[4][2] = {};

  auto stage = [&](int buf, int kt) {
    const int k0 = kt * 64;
#pragma unroll
    for (int i = 0; i < 2; ++i) {
      const int c = w * 2 + i;
      const int r = c * 8 + (ln >> 3);
      const int g = ln & 7;
      const int ko = k0 + ((g ^ (r & 7)) * 8);
      llds16(A + (size_t)(m0 + r) * Kd + ko, &As[buf][c * 512]);
      llds16(BT + (size_t)(n0 + r) * Kd + ko, &Bs[buf][c * 512]);
    }
  };
  stage(0, 0);
  __syncthreads();
  int cur = 0;
  for (int kt = 0; kt < Kd / 64; ++kt) {
    if (kt < Kd / 64 - 1) stage(cur ^ 1, kt + 1);
#pragma unroll
    for (int kk = 0; kk < 2; ++kk) {
      f16x8 af[4], bf[2];
#pragma unroll
      for (int mi = 0; mi < 4; ++mi) {
        const int r = wm * 64 + mi * 16 + (ln & 15);
        const int g = kk * 4 + (ln >> 4);
        af[mi] = *(const f16x8*)(&As[cur][r * 64 + ((g ^ (r & 7)) * 8)]);
      }
#pragma unroll
      for (int nf = 0; nf < 2; ++nf) {
        const int r = wn * 32 + nf * 16 + (ln & 15);
        const int g = kk * 4 + (ln >> 4);
        bf[nf] = *(const f16x8*)(&Bs[cur][r * 64 + ((g ^ (r & 7)) * 8)]);
      }
#pragma unroll
      for (int mi = 0; mi < 4; ++mi)
#pragma unroll
        for (int nf = 0; nf < 2; ++nf)
          acc[mi][nf] = __builtin_amdgcn_mfma_f32_16x16x32_f16(af[mi], bf[nf], acc[mi][nf], 0, 0, 0);
    }
    __syncthreads();
    cur ^= 1;
  }
  const float* bb = (Nd == 1024) ? b0 : (n0 < 1024 ? b0 : n0 < 2048 ? b1 : b2);
  const int nb = n0 & 1023;
  if (MODE == 0 && n0 >= 2048) {
    // V third: write transposed into Vt[(b,h), d, s], 8B packed along s
#pragma unroll
    for (int mi = 0; mi < 4; ++mi)
#pragma unroll
      for (int nf = 0; nf < 2; ++nf) {
        const int cl = wn * 32 + nf * 16 + (ln & 15);
        const int colg = n0 - 2048 + cl;
        const int hd = colg >> 6, d = colg & 63;
        const int row0 = m0 + wm * 64 + mi * 16 + (ln >> 4) * 4;
        const int bI = row0 >> 11, s = row0 & 2047;
        const float bias = bb[nb + cl];
        f16x4 pv;
#pragma unroll
        for (int r = 0; r < 4; ++r) pv[r] = (f16)(acc[mi][nf][r] + bias);
        *(f16x4*)(&Vt[((size_t)(bI * 16 + hd) * 64 + d) * SEQ + s]) = pv;
      }
  } else {
#pragma unroll
    for (int mi = 0; mi < 4; ++mi)
#pragma unroll
      for (int nf = 0; nf < 2; ++nf)
#pragma unroll
        for (int r = 0; r < 4; ++r) {
          const int row = m0 + wm * 64 + mi * 16 + (ln >> 4) * 4 + r;
          const int cl = wn * 32 + nf * 16 + (ln & 15);
          const float val = acc[mi][nf][r] + bb[nb + cl];
          if (MODE == 1)
            ((float*)Cout)[(size_t)row * Nd + n0 + cl] = val;
          else
            ((f16*)Cout)[(size_t)row * Nd + n0 + cl] = (f16)val;
        }
  }
}

// ---- fused sigmoid attention: 32x32 MFMA, 32 q-rows/wave, in-register P ----
__global__ __launch_bounds__(256, 2) void k_attn(const f16* __restrict__ QKV,
                                                 const f16* __restrict__ Vt,
                                                 f16* __restrict__ ctx) {
  __shared__ __align__(16) f16 Ks[2][4096];  // [kv 64][d 64] swizzled
  __shared__ __align__(16) f16 Vs[2][4096];  // [d 64][kv 64] swizzled
  int id = blockIdx.x;
  id = (id & 7) * 64 + (id >> 3);  // XCD swizzle (grid 512)
  const int qt = id & 15, hd = (id >> 4) & 15, b = id >> 8;
  const int tid = threadIdx.x, w = tid >> 6, ln = tid & 63;
  const int lh = ln >> 5, l31 = ln & 31;
  const int q0 = qt * 128 + w * 32;
  const f16* Qb = QKV + ((size_t)b * SEQ) * NQKV + hd * 64;
  const f16* Kb = QKV + ((size_t)b * SEQ) * NQKV + 1024 + hd * 64;
  const f16* Vtb = Vt + (size_t)(b * N_HEAD + hd) * 64 * SEQ;

  // Q B-fragments in registers: lane q-row = q0 + l31, d = kk*16 + lh*8 + j
  f16x8 aq[4];
#pragma unroll
  for (int kk = 0; kk < 4; ++kk)
    aq[kk] = *(const f16x8*)(Qb + (size_t)(q0 + l31) * NQKV + kk * 16 + lh * 8);

  f32x16 oacc0 = {}, oacc1 = {};

  auto stage = [&](int buf, int kt) {
    const int kv0 = kt * 64;
#pragma unroll
    for (int i = 0; i < 2; ++i) {
      const int c = w * 2 + i;
      const int r = c * 8 + (ln >> 3);
      const int g = ln & 7;
      llds16(Kb + (size_t)(kv0 + r) * NQKV + ((g ^ (r & 7)) * 8), &Ks[buf][c * 512]);
      llds16(Vtb + (size_t)r * SEQ + kv0 + ((g ^ (r & 7)) * 8), &Vs[buf][c * 512]);
    }
  };
  stage(0, 0);
  __syncthreads();
  int cur = 0;
  for (int kt = 0; kt < SEQ / 64; ++kt) {
    if (kt < SEQ / 64 - 1) stage(cur ^ 1, kt + 1);
    // S^T = K @ Q^T : lane q = l31 fixed; kv = kvt*32 + (reg&3)+8*(reg>>2)+4*lh
    f32x16 sacc0 = {}, sacc1 = {};
#pragma unroll
    for (int kk = 0; kk < 4; ++kk) {
      {
        const int r = l31;
        const f16x8 ak = *(const f16x8*)(&Ks[cur][r * 64 + (((kk * 2 + lh) ^ (r & 7)) * 8)]);
        sacc0 = __builtin_amdgcn_mfma_f32_32x32x16_f16(ak, aq[kk], sacc0, 0, 0, 0);
      }
      {
        const int r = 32 + l31;
        const f16x8 ak = *(const f16x8*)(&Ks[cur][r * 64 + (((kk * 2 + lh) ^ (r & 7)) * 8)]);
        sacc1 = __builtin_amdgcn_mfma_f32_32x32x16_f16(ak, aq[kk], sacc1, 0, 0, 0);
      }
    }
    // P = sigmoid(S/8) packed to f16 in-register; permlane32_swap builds PV A-frags
    f16x8 pa[4];
#pragma unroll
    for (int kvt = 0; kvt < 2; ++kvt) {
      const f32x16 sc = kvt ? sacc1 : sacc0;
#pragma unroll
      for (int hf = 0; hf < 2; ++hf) {
        const int b8 = hf * 8;
        u32 X = pk2(SIG(sc[b8 + 0]), SIG(sc[b8 + 1]));
        u32 Y = pk2(SIG(sc[b8 + 2]), SIG(sc[b8 + 3]));
        u32 Z = pk2(SIG(sc[b8 + 4]), SIG(sc[b8 + 5]));
        u32 W = pk2(SIG(sc[b8 + 6]), SIG(sc[b8 + 7]));
        asm volatile("v_permlane32_swap_b32 %0, %1" : "+v"(X), "+v"(Z));
        asm volatile("v_permlane32_swap_b32 %0, %1" : "+v"(Y), "+v"(W));
        union { u32 uw[4]; f16x8 v; } u;
        u.uw[0] = X; u.uw[1] = Y; u.uw[2] = Z; u.uw[3] = W;
        pa[kvt * 2 + hf] = u.v;
      }
    }
    // O += P @ V : B-frag from Vs rows d, k-rows kv = c*16 + lh*8 + j
#pragma unroll
    for (int c = 0; c < 4; ++c) {
      {
        const int d = l31;
        const f16x8 bv = *(const f16x8*)(&Vs[cur][d * 64 + (((c * 2 + lh) ^ (d & 7)) * 8)]);
        oacc0 = __builtin_amdgcn_mfma_f32_32x32x16_f16(pa[c], bv, oacc0, 0, 0, 0);
      }
      {
        const int d = 32 + l31;
        const f16x8 bv = *(const f16x8*)(&Vs[cur][d * 64 + (((c * 2 + lh) ^ (d & 7)) * 8)]);
        oacc1 = __builtin_amdgcn_mfma_f32_32x32x16_f16(pa[c], bv, oacc1, 0, 0, 0);
      }
    }
    __syncthreads();
    cur ^= 1;
  }
  // write ctx: col = hd*64 + dt*32 + l31, row q = q0 + (r&3)+8*(r>>2)+4*lh
#pragma unroll
  for (int dt = 0; dt < 2; ++dt) {
    const int dcol = hd * 64 + dt * 32 + l31;
#pragma unroll
    for (int r = 0; r < 16; ++r) {
      const int ql = (r & 3) + 8 * (r >> 2) + 4 * lh;
      const float v = dt ? oacc1[r] : oacc0[r];
      ctx[((size_t)b * SEQ + q0 + ql) * D_MODEL + dcol] = (f16)v;
    }
  }
}

extern "C" void kernel_launch(void* const* d_in, const int* in_sizes, int n_in,
                              void* d_out, int out_size, void* d_ws, size_t ws_size,
                              hipStream_t stream) {
  (void)in_sizes; (void)n_in; (void)out_size; (void)ws_size;
  const float* q  = (const float*)d_in[0];
  const float* k  = (const float*)d_in[1];
  const float* v  = (const float*)d_in[2];
  const float* Wq = (const float*)d_in[3];
  const float* bq = (const float*)d_in[4];
  const float* Wk = (const float*)d_in[5];
  const float* bk = (const float*)d_in[6];
  const float* Wv = (const float*)d_in[7];
  const float* bv = (const float*)d_in[8];
  const float* Wo = (const float*)d_in[9];
  const float* bo = (const float*)d_in[10];
  float* out = (float*)d_out;

  char* p = (char*)d_ws;
  const size_t SZ_X = (size_t)MTOT * D_MODEL * sizeof(f16);  // 8 MB
  f16* qb    = (f16*)p; p += 3 * SZ_X;                       // q,k,v contiguous
  f16* WqkvT = (f16*)p; p += 3 * (size_t)1024 * 1024 * sizeof(f16);
  f16* WoT   = (f16*)p; p += (size_t)1024 * 1024 * sizeof(f16);
  f16* QKVb  = (f16*)p; p += (size_t)MTOT * NQKV * sizeof(f16);  // 24 MB
  f16* Vtb   = (f16*)p; p += SZ_X;
  f16* ctx   = (f16*)p; p += SZ_X;
  f16* kb = qb + (size_t)MTOT * D_MODEL;
  f16* vb = kb + (size_t)MTOT * D_MODEL;

  k_cvt3<<<3 * MTOT * D_MODEL / 2048, 256, 0, stream>>>(q, k, v, qb);
  k_tw<<<dim3(32, 32, 4), dim3(32, 8), 0, stream>>>(Wq, Wk, Wv, Wo, WqkvT, WoT);
  k_gemm<NQKV, 0><<<(MTOT / 128) * (NQKV / 128), 512, 0, stream>>>(
      qb, kb, vb, WqkvT, bq, bk, bv, QKVb, Vtb);
  k_attn<<<(SEQ / 128) * N_HEAD * BATCH, 256, 0, stream>>>(QKVb, Vtb, ctx);
  k_gemm<1024, 1><<<(MTOT / 128) * (1024 / 128), 512, 0, stream>>>(
      ctx, ctx, ctx, WoT, bo, bo, bo, out, nullptr);
}